// Round 3
// baseline (1352.593 us; speedup 1.0000x reference)
//
#include <hip/hip_runtime.h>

#define MM 50000
#define EE 800000
#define C  64
#define NWIN (EE / 64)   // 12500 windows of 64 sorted edges
#define CPAD 53248       // 1024*52 padded counts/offsets region
#define NPB  782         // node-proj blocks (64 nodes each)
#define CNTB 3125        // count blocks (800000/256)

// ---------- helpers ----------

__device__ __forceinline__ float fast_gelu(float x) {
    // x * sigmoid(1.5957691*(x + 0.044715 x^3)); max abs err ~2e-4 vs erf-gelu
    float x3 = x * x * x;
    float u  = 1.5957691216057308f * fmaf(0.044715f, x3, x);
    float ex = __expf(-u);
    float s  = __builtin_amdgcn_rcpf(1.0f + ex);
    return x * s;
}

__device__ __forceinline__ void ln_gelu(float* h, const float* __restrict__ g,
                                        const float* __restrict__ b) {
    float mu = 0.f;
#pragma unroll
    for (int j = 0; j < C; j++) mu += h[j];
    mu *= (1.0f / C);
    float var = 0.f;
#pragma unroll
    for (int j = 0; j < C; j++) { float d = h[j] - mu; var = fmaf(d, d, var); }
    var *= (1.0f / C);
    float rs = __builtin_amdgcn_rsqf(var + 1e-5f);
#pragma unroll
    for (int j = 0; j < C; j++) {
        float t = fmaf((h[j] - mu) * rs, g[j], b[j]);
        h[j] = fast_gelu(t);
    }
}

// round-to-nearest-even f32->bf16 pair pack (values bounded, no NaN concern)
__device__ __forceinline__ unsigned int bfpack(float a0, float a1) {
    unsigned int u0 = __float_as_uint(a0);
    u0 = (u0 + 0x7fffu + ((u0 >> 16) & 1u)) >> 16;
    unsigned int u1 = __float_as_uint(a1);
    u1 = (u1 + 0x7fffu + ((u1 >> 16) & 1u)) & 0xffff0000u;
    return u0 | u1;
}

// ---------- kernel 1: node projections (4 nodes/thread) + edge count, fused ----------

__global__ __launch_bounds__(256) void proj_count(
    const float* __restrict__ feat,
    const float* __restrict__ W1, const float* __restrict__ W2,
    const float* __restrict__ W3,
    float* __restrict__ w1, float* __restrict__ w2, float* __restrict__ w3,
    const int* __restrict__ tgt, int* __restrict__ counts) {
    int bid = blockIdx.x;
    if (bid < NPB) {
        int grp = threadIdx.x >> 4, cg = threadIdx.x & 15;
        int n0 = bid * 64 + grp * 4;
        const float4* W14 = (const float4*)W1;
        const float4* W24 = (const float4*)W2;
        const float4* W34 = (const float4*)W3;
        float4 a1[4], a2[4], a3[4];
#pragma unroll
        for (int m = 0; m < 4; m++) {
            a1[m] = make_float4(0, 0, 0, 0);
            a2[m] = make_float4(0, 0, 0, 0);
            a3[m] = make_float4(0, 0, 0, 0);
        }
        int nn[4];
#pragma unroll
        for (int m = 0; m < 4; m++) nn[m] = min(n0 + m, MM - 1);  // clamp loads
#pragma unroll
        for (int kk = 0; kk < 16; kk++) {
            float4 f[4];
#pragma unroll
            for (int m = 0; m < 4; m++)
                f[m] = ((const float4*)(feat + (size_t)nn[m] * C))[kk];
#pragma unroll
            for (int r = 0; r < 4; r++) {
                int k = kk * 4 + r;
                float4 u1 = W14[k * 16 + cg];
                float4 u2 = W24[k * 16 + cg];
                float4 u3 = W34[k * 16 + cg];
#pragma unroll
                for (int m = 0; m < 4; m++) {
                    float fv = (&f[m].x)[r];
                    a1[m].x = fmaf(fv, u1.x, a1[m].x); a1[m].y = fmaf(fv, u1.y, a1[m].y);
                    a1[m].z = fmaf(fv, u1.z, a1[m].z); a1[m].w = fmaf(fv, u1.w, a1[m].w);
                    a2[m].x = fmaf(fv, u2.x, a2[m].x); a2[m].y = fmaf(fv, u2.y, a2[m].y);
                    a2[m].z = fmaf(fv, u2.z, a2[m].z); a2[m].w = fmaf(fv, u2.w, a2[m].w);
                    a3[m].x = fmaf(fv, u3.x, a3[m].x); a3[m].y = fmaf(fv, u3.y, a3[m].y);
                    a3[m].z = fmaf(fv, u3.z, a3[m].z); a3[m].w = fmaf(fv, u3.w, a3[m].w);
                }
            }
        }
#pragma unroll
        for (int m = 0; m < 4; m++) {
            if (n0 + m < MM) {
                ((float4*)w1)[(size_t)(n0 + m) * 16 + cg] = a1[m];
                ((float4*)w2)[(size_t)(n0 + m) * 16 + cg] = a2[m];
                ((float4*)w3)[(size_t)(n0 + m) * 16 + cg] = a3[m];
            }
        }
    } else {
        int e = (bid - NPB) * 256 + threadIdx.x;  // exactly EE threads
        atomicAdd(&counts[tgt[e]], 1);
    }
}

// ---------- scan: single block, 52 elems/thread, int4 I/O ----------

#define SCHUNK 52  // 1024*52 = 53248 >= MM+1

__global__ __launch_bounds__(1024) void scan_kernel(int* __restrict__ counts_cursor,
                                                    int* __restrict__ offsets) {
    __shared__ int sums[1024];
    int tid = threadIdx.x;
    int base = tid * SCHUNK;
    int v[SCHUNK];
    const int4* c4 = (const int4*)(counts_cursor + base);
#pragma unroll
    for (int i = 0; i < SCHUNK / 4; i++) {
        int4 q = c4[i];
        v[4 * i] = q.x; v[4 * i + 1] = q.y; v[4 * i + 2] = q.z; v[4 * i + 3] = q.w;
    }
    int s = 0;
#pragma unroll
    for (int k = 0; k < SCHUNK; k++) { int t = v[k]; v[k] = s; s += t; }
    int my_total = s;
    sums[tid] = s;
    __syncthreads();
    for (int off = 1; off < 1024; off <<= 1) {
        int t = (tid >= off) ? sums[tid - off] : 0;
        __syncthreads();
        sums[tid] += t;
        __syncthreads();
    }
    int chunk_off = sums[tid] - my_total;
    int4* o4 = (int4*)(offsets + base);
    int4* cc4 = (int4*)(counts_cursor + base);
#pragma unroll
    for (int i = 0; i < SCHUNK / 4; i++) {
        int4 q = make_int4(v[4 * i] + chunk_off, v[4 * i + 1] + chunk_off,
                           v[4 * i + 2] + chunk_off, v[4 * i + 3] + chunk_off);
        o4[i] = q;
        cc4[i] = q;
    }
}

// ---------- scatter into sorted-by-target order ----------

__global__ __launch_bounds__(256) void scatter_kernel(
    const int* __restrict__ src, const int* __restrict__ tgt,
    int* __restrict__ cursor, int* __restrict__ se,
    int* __restrict__ ss, int* __restrict__ st) {
    int e = blockIdx.x * 256 + threadIdx.x;
    if (e >= EE) return;
    int t = tgt[e];
    int pos = atomicAdd(&cursor[t], 1);
    se[pos] = e;
    ss[pos] = src[e];
    st[pos] = t;
}

// ---------- main: per-wave windowed segmented softmax-aggregate ----------
// Phase 1: thread-per-edge MLP; layer 2 in 4 chunks of 16 channels (no spill),
// pre-LN d2 stored to LDS as bf16 (8.4 KB); LN stats via sum/sumsq; LN+GELU
// deferred to phase-2 read (each element consumed exactly once).

__global__ __launch_bounds__(64, 4) void main_kernel(
    const int* __restrict__ se, const int* __restrict__ ss,
    const int* __restrict__ st, const int* __restrict__ offsets,
    const float* __restrict__ hood,
    const float* __restrict__ Wd1, const float* __restrict__ bd1,
    const float* __restrict__ g1, const float* __restrict__ b1,
    const float* __restrict__ Wd2, const float* __restrict__ bd2,
    const float* __restrict__ g2, const float* __restrict__ b2,
    const float* __restrict__ w1, const float* __restrict__ w2,
    const float* __restrict__ w3,
    float* __restrict__ den, float* __restrict__ out) {
    __shared__ unsigned short d2h[64][66];
    __shared__ float2 musrs[64];
    int lane = threadIdx.x;
    int p0 = blockIdx.x * 64;
    int p = p0 + lane;

    int eid = se[p];
    int s_my = ss[p];
    int t_my = st[p];
    float x0 = hood[3 * eid], x1 = hood[3 * eid + 1], x2 = hood[3 * eid + 2];

    // ---- layer 1 ----
    float h[C];
#pragma unroll
    for (int j = 0; j < C; j++)
        h[j] = fmaf(x0, Wd1[j], fmaf(x1, Wd1[C + j], fmaf(x2, Wd1[2 * C + j], bd1[j])));
    ln_gelu(h, g1, b1);

    // ---- layer 2, chunked; keep VGPRs at h[64]+acc[16] ----
    float sum = 0.f, sumsq = 0.f;
    unsigned int* row = (unsigned int*)&d2h[lane][0];
#pragma unroll 1
    for (int j0 = 0; j0 < C; j0 += 16) {
        float acc[16];
#pragma unroll
        for (int j = 0; j < 16; j++) acc[j] = bd2[j0 + j];
#pragma unroll
        for (int k = 0; k < C; k++) {
            float hk = h[k];
#pragma unroll
            for (int j = 0; j < 16; j++)
                acc[j] = fmaf(hk, Wd2[k * C + j0 + j], acc[j]);
        }
#pragma unroll
        for (int j2 = 0; j2 < 8; j2++) {
            float a0 = acc[2 * j2], a1v = acc[2 * j2 + 1];
            sum += a0 + a1v;
            sumsq = fmaf(a0, a0, fmaf(a1v, a1v, sumsq));
            row[j0 / 2 + j2] = bfpack(a0, a1v);
        }
    }
    float mu = sum * (1.0f / C);
    float var = sumsq * (1.0f / C) - mu * mu;
    float rs = __builtin_amdgcn_rsqf(var + 1e-5f);
    musrs[lane] = make_float2(mu, rs);
    __syncthreads();

    // ---- phase 2: lane = channel ----
    float g2v = g2[lane], b2v = b2[lane];
    int cur_t = -1;
    bool owned = false;
    float den_a = 0.f, num_a = 0.f, w1v = 0.f;
#pragma unroll 4
    for (int i = 0; i < 64; i++) {
        int ti = __shfl(t_my, i);
        int si = __shfl(s_my, i);
        if (ti != cur_t) {
            if (cur_t >= 0) {
                size_t o = (size_t)cur_t * C + lane;
                if (owned) out[o] = num_a / den_a;
                else { unsafeAtomicAdd(&den[o], den_a); unsafeAtomicAdd(&out[o], num_a); }
            }
            cur_t = ti; den_a = 0.f; num_a = 0.f;
            w1v = w1[(size_t)ti * C + lane];
            int o0 = offsets[ti], o1 = offsets[ti + 1];
            owned = (o0 >= p0) && (o1 <= p0 + 64);
        }
        float raw = __uint_as_float(((unsigned int)d2h[i][lane]) << 16);
        float2 ms = musrs[i];
        float dv = fast_gelu(fmaf((raw - ms.x) * ms.y, g2v, b2v));
        float w2v = w2[(size_t)si * C + lane];
        float w3v = w3[(size_t)si * C + lane];
        float ee = __expf(w1v - w2v + dv);
        den_a += ee;
        num_a = fmaf(ee, w3v + dv, num_a);
    }
    {
        size_t o = (size_t)cur_t * C + lane;
        if (owned) out[o] = num_a / den_a;
        else { unsafeAtomicAdd(&den[o], den_a); unsafeAtomicAdd(&out[o], num_a); }
    }
}

// ---------- finalize: divide straddler targets (den > 0) ----------

__global__ __launch_bounds__(256) void finalize(float4* __restrict__ out,
                                                const float4* __restrict__ den) {
    int i = blockIdx.x * 256 + threadIdx.x;
    if (i >= MM * (C / 4)) return;
    float4 dn = den[i];
    if (dn.x == 0.f && dn.y == 0.f && dn.z == 0.f && dn.w == 0.f) return;
    float4 nm = out[i];
    float4 o;
    o.x = (dn.x != 0.f) ? nm.x / dn.x : nm.x;
    o.y = (dn.y != 0.f) ? nm.y / dn.y : nm.y;
    o.z = (dn.z != 0.f) ? nm.z / dn.z : nm.z;
    o.w = (dn.w != 0.f) ? nm.w / dn.w : nm.w;
    out[i] = o;
}

// ---------- launch ----------

extern "C" void kernel_launch(void* const* d_in, const int* in_sizes, int n_in,
                              void* d_out, int out_size, void* d_ws, size_t ws_size,
                              hipStream_t stream) {
    const int*   src  = (const int*)d_in[0];
    const int*   tgt  = (const int*)d_in[1];
    const float* feat = (const float*)d_in[2];
    const float* hood = (const float*)d_in[3];
    const float* Wd1  = (const float*)d_in[4];
    const float* bd1  = (const float*)d_in[5];
    const float* g1   = (const float*)d_in[6];
    const float* b1   = (const float*)d_in[7];
    const float* Wd2  = (const float*)d_in[8];
    const float* bd2  = (const float*)d_in[9];
    const float* g2   = (const float*)d_in[10];
    const float* b2   = (const float*)d_in[11];
    const float* W1   = (const float*)d_in[12];
    const float* W2   = (const float*)d_in[13];
    const float* W3   = (const float*)d_in[14];

    float* w1  = (float*)d_ws;
    float* w2  = w1 + (size_t)MM * C;
    float* w3  = w2 + (size_t)MM * C;
    float* den = w3 + (size_t)MM * C;
    int* counts_cursor = (int*)(den + (size_t)MM * C);
    int* offsets = counts_cursor + CPAD;
    int* se = offsets + CPAD;
    int* ss = se + EE;
    int* st = ss + EE;
    float* out = (float*)d_out;

    // one memset covers den + counts (adjacent); out zeroed separately
    hipMemsetAsync(den, 0, (size_t)MM * C * sizeof(float) + CPAD * sizeof(int), stream);
    hipMemsetAsync(out, 0, (size_t)MM * C * sizeof(float), stream);

    proj_count<<<NPB + CNTB, 256, 0, stream>>>(feat, W1, W2, W3, w1, w2, w3,
                                               tgt, counts_cursor);
    scan_kernel<<<1, 1024, 0, stream>>>(counts_cursor, offsets);
    scatter_kernel<<<(EE + 255) / 256, 256, 0, stream>>>(src, tgt, counts_cursor, se, ss, st);
    main_kernel<<<NWIN, 64, 0, stream>>>(se, ss, st, offsets, hood,
                                         Wd1, bd1, g1, b1, Wd2, bd2, g2, b2,
                                         w1, w2, w3, den, out);
    finalize<<<(MM * 16 + 255) / 256, 256, 0, stream>>>((float4*)out, (const float4*)den);
}

// Round 4
// 1015.549 us; speedup vs baseline: 1.3319x; 1.3319x over previous
//
#include <hip/hip_runtime.h>

#define MM 50000
#define EE 800000
#define C  64
#define NWIN (EE / 64)   // 12500 windows of 64 sorted edges

// ---------- helpers ----------

__device__ __forceinline__ float fast_gelu(float x) {
    // x * sigmoid(1.5957691*(x + 0.044715 x^3)); max abs err ~2e-4 vs erf-gelu
    float x3 = x * x * x;
    float u  = 1.5957691216057308f * fmaf(0.044715f, x3, x);
    float ex = __expf(-u);
    float s  = __builtin_amdgcn_rcpf(1.0f + ex);
    return x * s;
}

// round-to-nearest-even f32->bf16 pair pack (a0 -> low16, a1 -> high16)
__device__ __forceinline__ unsigned int bfpack(float a0, float a1) {
    unsigned int u0 = __float_as_uint(a0);
    u0 = (u0 + 0x7fffu + ((u0 >> 16) & 1u)) >> 16;
    unsigned int u1 = __float_as_uint(a1);
    u1 = (u1 + 0x7fffu + ((u1 >> 16) & 1u)) & 0xffff0000u;
    return u0 | u1;
}

// ---------- kernel 1: node projections (round-2 form, w2/w3 interleaved) ----------

__global__ __launch_bounds__(256) void node_proj(
    const float* __restrict__ feat,
    const float* __restrict__ W1, const float* __restrict__ W2,
    const float* __restrict__ W3,
    float* __restrict__ w1, float* __restrict__ w23) {
    int tid = blockIdx.x * 256 + threadIdx.x;
    int n = tid >> 4, cg = tid & 15;
    if (n >= MM) return;
    const float4* f4  = (const float4*)(feat + (size_t)n * C);
    const float4* W14 = (const float4*)W1;
    const float4* W24 = (const float4*)W2;
    const float4* W34 = (const float4*)W3;
    float4 a1 = {0, 0, 0, 0}, a2 = {0, 0, 0, 0}, a3 = {0, 0, 0, 0};
#pragma unroll
    for (int kk = 0; kk < 16; kk++) {
        float4 f = f4[kk];
#pragma unroll
        for (int r = 0; r < 4; r++) {
            float fv = (&f.x)[r];
            int k = kk * 4 + r;
            float4 u1 = W14[k * 16 + cg];
            a1.x = fmaf(fv, u1.x, a1.x); a1.y = fmaf(fv, u1.y, a1.y);
            a1.z = fmaf(fv, u1.z, a1.z); a1.w = fmaf(fv, u1.w, a1.w);
            float4 u2 = W24[k * 16 + cg];
            a2.x = fmaf(fv, u2.x, a2.x); a2.y = fmaf(fv, u2.y, a2.y);
            a2.z = fmaf(fv, u2.z, a2.z); a2.w = fmaf(fv, u2.w, a2.w);
            float4 u3 = W34[k * 16 + cg];
            a3.x = fmaf(fv, u3.x, a3.x); a3.y = fmaf(fv, u3.y, a3.y);
            a3.z = fmaf(fv, u3.z, a3.z); a3.w = fmaf(fv, u3.w, a3.w);
        }
    }
    ((float4*)w1)[(size_t)n * 16 + cg] = a1;
    // interleave: w23[n*128 + 2c] = w2_c, w23[n*128 + 2c+1] = w3_c
    float4 lo = make_float4(a2.x, a3.x, a2.y, a3.y);
    float4 hi = make_float4(a2.z, a3.z, a2.w, a3.w);
    ((float4*)w23)[(size_t)n * 32 + 2 * cg]     = lo;
    ((float4*)w23)[(size_t)n * 32 + 2 * cg + 1] = hi;
}

// ---------- counting sort: count / scan / scatter (round-2 forms) ----------

__global__ __launch_bounds__(256) void count_kernel(const int* __restrict__ tgt,
                                                    int* __restrict__ counts) {
    int e = blockIdx.x * 256 + threadIdx.x;
    if (e < EE) atomicAdd(&counts[tgt[e]], 1);
}

#define CHUNK 49  // 1024*49 = 50176 >= MM

__global__ __launch_bounds__(1024) void scan_kernel(int* __restrict__ counts_cursor,
                                                    int* __restrict__ offsets) {
    __shared__ int sums[1024];
    int tid = threadIdx.x;
    int base = tid * CHUNK;
    int loc[CHUNK];
    int s = 0;
#pragma unroll
    for (int k = 0; k < CHUNK; k++) {
        int v = (base + k < MM) ? counts_cursor[base + k] : 0;
        loc[k] = s;
        s += v;
    }
    int my_total = s;
    sums[tid] = s;
    __syncthreads();
    for (int off = 1; off < 1024; off <<= 1) {
        int v = (tid >= off) ? sums[tid - off] : 0;
        __syncthreads();
        sums[tid] += v;
        __syncthreads();
    }
    int chunk_off = sums[tid] - my_total;  // exclusive prefix of chunk totals
#pragma unroll
    for (int k = 0; k < CHUNK; k++) {
        if (base + k < MM) {
            int o = chunk_off + loc[k];
            offsets[base + k] = o;
            counts_cursor[base + k] = o;  // reused as scatter cursor
        }
    }
    if (tid == 0) offsets[MM] = sums[1023];
}

__global__ __launch_bounds__(256) void scatter_kernel(
    const int* __restrict__ src, const int* __restrict__ tgt,
    int* __restrict__ cursor, int* __restrict__ se,
    int* __restrict__ ss, int* __restrict__ st) {
    int e = blockIdx.x * 256 + threadIdx.x;
    if (e >= EE) return;
    int t = tgt[e];
    int pos = atomicAdd(&cursor[t], 1);
    se[pos] = e;
    ss[pos] = src[e];
    st[pos] = t;
}

// ---------- main: per-wave windowed segmented softmax-aggregate ----------
// Low-VGPR by construction: h lives only in LDS (bf16 pairs, stride-33 rows);
// layer-1 stats via a stats-only pass + recompute; layer-2 in 4 macro chunks
// with named d2 register arrays (all indices compile-time); LN2 deferred to
// phase-2 read with mu/rs broadcast by shuffle.

__global__ __launch_bounds__(64) void main_kernel(
    const int* __restrict__ se, const int* __restrict__ ss,
    const int* __restrict__ st, const int* __restrict__ offsets,
    const float* __restrict__ hood,
    const float* __restrict__ Wd1, const float* __restrict__ bd1,
    const float* __restrict__ g1, const float* __restrict__ b1,
    const float* __restrict__ Wd2, const float* __restrict__ bd2,
    const float* __restrict__ g2, const float* __restrict__ b2,
    const float* __restrict__ w1, const float* __restrict__ w23,
    float* __restrict__ den, float* __restrict__ out) {
    __shared__ unsigned int hbuf[64][33];  // 8448 B
    int lane = threadIdx.x;
    int p0 = blockIdx.x * 64;
    int p = p0 + lane;

    int eid = se[p];
    int s_my = ss[p];
    int t_my = st[p];
    float x0 = hood[3 * eid], x1 = hood[3 * eid + 1], x2 = hood[3 * eid + 2];

    // ---- pass A: layer-1 LN stats only (no storage) ----
    float sum = 0.f, sumsq = 0.f;
#pragma unroll
    for (int j = 0; j < C; j++) {
        float hp = fmaf(x0, Wd1[j], fmaf(x1, Wd1[C + j], fmaf(x2, Wd1[2 * C + j], bd1[j])));
        sum += hp;
        sumsq = fmaf(hp, hp, sumsq);
    }
    float mu1 = sum * (1.0f / C);
    float var1 = fmaf(-mu1, mu1, sumsq * (1.0f / C));
    float rs1 = __builtin_amdgcn_rsqf(var1 + 1e-5f);

    // ---- pass B: recompute h, LN1+GELU, pack bf16 pairs -> LDS ----
#pragma unroll
    for (int j2 = 0; j2 < 32; j2++) {
        int j = 2 * j2;
        float hp0 = fmaf(x0, Wd1[j], fmaf(x1, Wd1[C + j], fmaf(x2, Wd1[2 * C + j], bd1[j])));
        float hp1 = fmaf(x0, Wd1[j + 1],
                         fmaf(x1, Wd1[C + j + 1], fmaf(x2, Wd1[2 * C + j + 1], bd1[j + 1])));
        float t0 = fmaf((hp0 - mu1) * rs1, g1[j], b1[j]);
        float t1 = fmaf((hp1 - mu1) * rs1, g1[j + 1], b1[j + 1]);
        hbuf[lane][j2] = bfpack(fast_gelu(t0), fast_gelu(t1));
    }

    // ---- layer 2: 4 chunks of 16 channels; h from LDS; d2 packs in regs ----
    float sum2 = 0.f, sumsq2 = 0.f;
    unsigned int d2p0[8], d2p1[8], d2p2[8], d2p3[8];

#define CHUNK_BODY(J0, DST)                                                   \
    {                                                                         \
        float acc[16];                                                        \
        _Pragma("unroll")                                                     \
        for (int j = 0; j < 16; j++) acc[j] = bd2[(J0) + j];                  \
        _Pragma("unroll")                                                     \
        for (int k2 = 0; k2 < 32; k2++) {                                     \
            unsigned int hu = hbuf[lane][k2];                                 \
            float h0 = __uint_as_float(hu << 16);                             \
            float h1 = __uint_as_float(hu & 0xffff0000u);                     \
            _Pragma("unroll")                                                 \
            for (int j = 0; j < 16; j++) {                                    \
                acc[j] = fmaf(h0, Wd2[(2 * k2) * C + (J0) + j], acc[j]);      \
                acc[j] = fmaf(h1, Wd2[(2 * k2 + 1) * C + (J0) + j], acc[j]);  \
            }                                                                 \
        }                                                                     \
        _Pragma("unroll")                                                     \
        for (int j2 = 0; j2 < 8; j2++) {                                      \
            float a0 = acc[2 * j2], a1v = acc[2 * j2 + 1];                    \
            sum2 += a0 + a1v;                                                 \
            sumsq2 = fmaf(a0, a0, fmaf(a1v, a1v, sumsq2));                    \
            DST[j2] = bfpack(a0, a1v);                                        \
        }                                                                     \
    }

    CHUNK_BODY(0, d2p0)
    CHUNK_BODY(16, d2p1)
    CHUNK_BODY(32, d2p2)
    CHUNK_BODY(48, d2p3)
#undef CHUNK_BODY

    // h fully consumed -> overwrite own row with packed d2 (lane-private, no barrier)
#pragma unroll
    for (int q = 0; q < 8; q++) {
        hbuf[lane][q]      = d2p0[q];
        hbuf[lane][q + 8]  = d2p1[q];
        hbuf[lane][q + 16] = d2p2[q];
        hbuf[lane][q + 24] = d2p3[q];
    }
    float mu2 = sum2 * (1.0f / C);
    float var2 = fmaf(-mu2, mu2, sumsq2 * (1.0f / C));
    float rs2 = __builtin_amdgcn_rsqf(var2 + 1e-5f);
    __syncthreads();

    // ---- phase 2: lane = channel, iterate the window's sorted edges ----
    float g2v = g2[lane], b2v = b2[lane];
    int cur_t = -1;
    bool owned = false;
    float den_a = 0.f, num_a = 0.f, w1v = 0.f;
#pragma unroll 4
    for (int i = 0; i < 64; i++) {
        int ti = __shfl(t_my, i);
        int si = __shfl(s_my, i);
        float mu_i = __shfl(mu2, i);
        float rs_i = __shfl(rs2, i);
        if (ti != cur_t) {
            if (cur_t >= 0) {
                size_t o = (size_t)cur_t * C + lane;
                if (owned) out[o] = num_a / den_a;
                else { unsafeAtomicAdd(&den[o], den_a); unsafeAtomicAdd(&out[o], num_a); }
            }
            cur_t = ti; den_a = 0.f; num_a = 0.f;
            w1v = w1[(size_t)ti * C + lane];
            int o0 = offsets[ti], o1 = offsets[ti + 1];
            owned = (o0 >= p0) && (o1 <= p0 + 64);
        }
        unsigned int hu = hbuf[i][lane >> 1];
        float raw = __uint_as_float((lane & 1) ? (hu & 0xffff0000u) : (hu << 16));
        float dv = fast_gelu(fmaf((raw - mu_i) * rs_i, g2v, b2v));
        float2 v23 = ((const float2*)w23)[(size_t)si * C + lane];
        float ee = __expf(w1v - v23.x + dv);
        den_a += ee;
        num_a = fmaf(ee, v23.y + dv, num_a);
    }
    {
        size_t o = (size_t)cur_t * C + lane;
        if (owned) out[o] = num_a / den_a;
        else { unsafeAtomicAdd(&den[o], den_a); unsafeAtomicAdd(&out[o], num_a); }
    }
}

// ---------- finalize: divide straddler targets (den > 0) ----------

__global__ __launch_bounds__(256) void finalize(float4* __restrict__ out,
                                                const float4* __restrict__ den) {
    int i = blockIdx.x * 256 + threadIdx.x;
    if (i >= MM * (C / 4)) return;
    float4 dn = den[i];
    if (dn.x == 0.f && dn.y == 0.f && dn.z == 0.f && dn.w == 0.f) return;
    float4 nm = out[i];
    float4 o;
    o.x = (dn.x != 0.f) ? nm.x / dn.x : nm.x;
    o.y = (dn.y != 0.f) ? nm.y / dn.y : nm.y;
    o.z = (dn.z != 0.f) ? nm.z / dn.z : nm.z;
    o.w = (dn.w != 0.f) ? nm.w / dn.w : nm.w;
    out[i] = o;
}

// ---------- launch ----------

extern "C" void kernel_launch(void* const* d_in, const int* in_sizes, int n_in,
                              void* d_out, int out_size, void* d_ws, size_t ws_size,
                              hipStream_t stream) {
    const int*   src  = (const int*)d_in[0];
    const int*   tgt  = (const int*)d_in[1];
    const float* feat = (const float*)d_in[2];
    const float* hood = (const float*)d_in[3];
    const float* Wd1  = (const float*)d_in[4];
    const float* bd1  = (const float*)d_in[5];
    const float* g1   = (const float*)d_in[6];
    const float* b1   = (const float*)d_in[7];
    const float* Wd2  = (const float*)d_in[8];
    const float* bd2  = (const float*)d_in[9];
    const float* g2   = (const float*)d_in[10];
    const float* b2   = (const float*)d_in[11];
    const float* W1   = (const float*)d_in[12];
    const float* W2   = (const float*)d_in[13];
    const float* W3   = (const float*)d_in[14];

    float* w1  = (float*)d_ws;
    float* w23 = w1 + (size_t)MM * C;           // interleaved w2/w3, 2*MM*C floats
    float* den = w23 + (size_t)2 * MM * C;
    int* counts_cursor = (int*)(den + (size_t)MM * C);
    int* offsets = counts_cursor + 50176;
    int* se = offsets + (MM + 1);
    int* ss = se + EE;
    int* st = ss + EE;
    float* out = (float*)d_out;

    hipMemsetAsync(counts_cursor, 0, 50176 * sizeof(int), stream);
    hipMemsetAsync(den, 0, (size_t)MM * C * sizeof(float), stream);
    hipMemsetAsync(out, 0, (size_t)MM * C * sizeof(float), stream);

    node_proj<<<(MM * 16 + 255) / 256, 256, 0, stream>>>(feat, W1, W2, W3, w1, w23);
    count_kernel<<<(EE + 255) / 256, 256, 0, stream>>>(tgt, counts_cursor);
    scan_kernel<<<1, 1024, 0, stream>>>(counts_cursor, offsets);
    scatter_kernel<<<(EE + 255) / 256, 256, 0, stream>>>(src, tgt, counts_cursor, se, ss, st);
    main_kernel<<<NWIN, 64, 0, stream>>>(se, ss, st, offsets, hood,
                                         Wd1, bd1, g1, b1, Wd2, bd2, g2, b2,
                                         w1, w23, den, out);
    finalize<<<(MM * 16 + 255) / 256, 256, 0, stream>>>((float4*)out, (const float4*)den);
}

// Round 5
// 527.882 us; speedup vs baseline: 2.5623x; 1.9238x over previous
//
#include <hip/hip_runtime.h>

#define MM 50000
#define EE 800000
#define C  64
#define NWIN (EE / 64)   // 12500 windows of 64 sorted edges

typedef _Float16 h2v __attribute__((ext_vector_type(2)));

#if __has_builtin(__builtin_amdgcn_fdot2)
#define FDOT2(A, B, ACC) __builtin_amdgcn_fdot2((A), (B), (ACC), false)
#else
#define FDOT2(A, B, ACC) fmaf((float)(A).x, (float)(B).x, fmaf((float)(A).y, (float)(B).y, (ACC)))
#endif

// ---------- helpers ----------

__device__ __forceinline__ float fast_gelu(float x) {
    // x * sigmoid(1.5957691*(x + 0.044715 x^3)); max abs err ~2e-4 vs erf-gelu
    float x3 = x * x * x;
    float u  = 1.5957691216057308f * fmaf(0.044715f, x3, x);
    float ex = __expf(-u);
    float s  = __builtin_amdgcn_rcpf(1.0f + ex);
    return x * s;
}

// round-to-nearest-even f32->bf16 pair pack (a0 -> low16, a1 -> high16)
__device__ __forceinline__ unsigned int bfpack(float a0, float a1) {
    unsigned int u0 = __float_as_uint(a0);
    u0 = (u0 + 0x7fffu + ((u0 >> 16) & 1u)) >> 16;
    unsigned int u1 = __float_as_uint(a1);
    u1 = (u1 + 0x7fffu + ((u1 >> 16) & 1u)) & 0xffff0000u;
    return u0 | u1;
}

// ---------- kernel 1: node projections (w2/w3 interleaved) ----------

__global__ __launch_bounds__(256) void node_proj(
    const float* __restrict__ feat,
    const float* __restrict__ W1, const float* __restrict__ W2,
    const float* __restrict__ W3,
    float* __restrict__ w1, float* __restrict__ w23) {
    int tid = blockIdx.x * 256 + threadIdx.x;
    int n = tid >> 4, cg = tid & 15;
    if (n >= MM) return;
    const float4* f4  = (const float4*)(feat + (size_t)n * C);
    const float4* W14 = (const float4*)W1;
    const float4* W24 = (const float4*)W2;
    const float4* W34 = (const float4*)W3;
    float4 a1 = {0, 0, 0, 0}, a2 = {0, 0, 0, 0}, a3 = {0, 0, 0, 0};
#pragma unroll
    for (int kk = 0; kk < 16; kk++) {
        float4 f = f4[kk];
#pragma unroll
        for (int r = 0; r < 4; r++) {
            float fv = (&f.x)[r];
            int k = kk * 4 + r;
            float4 u1 = W14[k * 16 + cg];
            a1.x = fmaf(fv, u1.x, a1.x); a1.y = fmaf(fv, u1.y, a1.y);
            a1.z = fmaf(fv, u1.z, a1.z); a1.w = fmaf(fv, u1.w, a1.w);
            float4 u2 = W24[k * 16 + cg];
            a2.x = fmaf(fv, u2.x, a2.x); a2.y = fmaf(fv, u2.y, a2.y);
            a2.z = fmaf(fv, u2.z, a2.z); a2.w = fmaf(fv, u2.w, a2.w);
            float4 u3 = W34[k * 16 + cg];
            a3.x = fmaf(fv, u3.x, a3.x); a3.y = fmaf(fv, u3.y, a3.y);
            a3.z = fmaf(fv, u3.z, a3.z); a3.w = fmaf(fv, u3.w, a3.w);
        }
    }
    ((float4*)w1)[(size_t)n * 16 + cg] = a1;
    float4 lo = make_float4(a2.x, a3.x, a2.y, a3.y);
    float4 hi = make_float4(a2.z, a3.z, a2.w, a3.w);
    ((float4*)w23)[(size_t)n * 32 + 2 * cg]     = lo;
    ((float4*)w23)[(size_t)n * 32 + 2 * cg + 1] = hi;
}

// ---------- counting sort: count / scan / scatter ----------

__global__ __launch_bounds__(256) void count_kernel(const int* __restrict__ tgt,
                                                    int* __restrict__ counts) {
    int e = blockIdx.x * 256 + threadIdx.x;
    if (e < EE) atomicAdd(&counts[tgt[e]], 1);
}

#define CHUNK 49  // 1024*49 = 50176 >= MM

__global__ __launch_bounds__(1024) void scan_kernel(int* __restrict__ counts_cursor,
                                                    int* __restrict__ offsets) {
    __shared__ int sums[1024];
    int tid = threadIdx.x;
    int base = tid * CHUNK;
    int loc[CHUNK];
    int s = 0;
#pragma unroll
    for (int k = 0; k < CHUNK; k++) {
        int v = (base + k < MM) ? counts_cursor[base + k] : 0;
        loc[k] = s;
        s += v;
    }
    int my_total = s;
    sums[tid] = s;
    __syncthreads();
    for (int off = 1; off < 1024; off <<= 1) {
        int v = (tid >= off) ? sums[tid - off] : 0;
        __syncthreads();
        sums[tid] += v;
        __syncthreads();
    }
    int chunk_off = sums[tid] - my_total;
#pragma unroll
    for (int k = 0; k < CHUNK; k++) {
        if (base + k < MM) {
            int o = chunk_off + loc[k];
            offsets[base + k] = o;
            counts_cursor[base + k] = o;
        }
    }
    if (tid == 0) offsets[MM] = sums[1023];
}

__global__ __launch_bounds__(256) void scatter_kernel(
    const int* __restrict__ src, const int* __restrict__ tgt,
    int* __restrict__ cursor, int* __restrict__ se,
    int* __restrict__ ss, int* __restrict__ st) {
    int e = blockIdx.x * 256 + threadIdx.x;
    if (e >= EE) return;
    int t = tgt[e];
    int pos = atomicAdd(&cursor[t], 1);
    se[pos] = e;
    ss[pos] = src[e];
    st[pos] = t;
}

// ---------- main: per-wave windowed segmented softmax-aggregate ----------
// Wd2 staged once per block into LDS as f16 k-pairs (broadcast reads).
// h packed to 32 f16x2 regs; layer-2 via v_dot2_f32_f16 (f32 accumulate).
// LN2+GELU applied in-register (exact f32 stats); final dv stored bf16 in LDS.
// Phase 2 is the lean r2 shape: unpack + exp + 2 fma per edge-channel.

__global__ __launch_bounds__(64) void main_kernel(
    const int* __restrict__ se, const int* __restrict__ ss,
    const int* __restrict__ st, const int* __restrict__ offsets,
    const float* __restrict__ hood,
    const float* __restrict__ Wd1, const float* __restrict__ bd1,
    const float* __restrict__ g1, const float* __restrict__ b1,
    const float* __restrict__ Wd2, const float* __restrict__ bd2,
    const float* __restrict__ g2, const float* __restrict__ b2,
    const float* __restrict__ w1, const float* __restrict__ w23,
    float* __restrict__ den, float* __restrict__ out) {
    __shared__ h2v wd2l[32][64];            // [k-pair][j] = {Wd2[2k][j], Wd2[2k+1][j]}, 8 KB
    __shared__ unsigned int d2buf[64][33];  // final dv, bf16 pairs along channel, 8.4 KB
    int lane = threadIdx.x;
    int p0 = blockIdx.x * 64;
    int p = p0 + lane;

    // ---- stage Wd2 -> LDS (coalesced; reads later are all-lane broadcast) ----
#pragma unroll 4
    for (int k2 = 0; k2 < 32; k2++) {
        float a0 = Wd2[(2 * k2) * C + lane];
        float a1 = Wd2[(2 * k2 + 1) * C + lane];
        h2v hv;
        hv.x = (_Float16)a0;
        hv.y = (_Float16)a1;
        wd2l[k2][lane] = hv;
    }

    int eid = se[p];
    int s_my = ss[p];
    int t_my = st[p];
    float x0 = hood[3 * eid], x1 = hood[3 * eid + 1], x2 = hood[3 * eid + 2];

    // ---- pass A: layer-1 LN stats (recompute is 3 fma/elem, cheaper than storage) ----
    float sum = 0.f, sumsq = 0.f;
#pragma unroll
    for (int j = 0; j < C; j++) {
        float hp = fmaf(x0, Wd1[j], fmaf(x1, Wd1[C + j], fmaf(x2, Wd1[2 * C + j], bd1[j])));
        sum += hp;
        sumsq = fmaf(hp, hp, sumsq);
    }
    float mu1 = sum * (1.0f / C);
    float var1 = fmaf(-mu1, mu1, sumsq * (1.0f / C));
    float rs1 = __builtin_amdgcn_rsqf(var1 + 1e-5f);

    // ---- pass B: recompute h, LN1+GELU, pack f16 pairs into registers ----
    h2v hreg[32];
#pragma unroll
    for (int j2 = 0; j2 < 32; j2++) {
        int j = 2 * j2;
        float hp0 = fmaf(x0, Wd1[j], fmaf(x1, Wd1[C + j], fmaf(x2, Wd1[2 * C + j], bd1[j])));
        float hp1 = fmaf(x0, Wd1[j + 1],
                         fmaf(x1, Wd1[C + j + 1], fmaf(x2, Wd1[2 * C + j + 1], bd1[j + 1])));
        float t0 = fast_gelu(fmaf((hp0 - mu1) * rs1, g1[j], b1[j]));
        float t1 = fast_gelu(fmaf((hp1 - mu1) * rs1, g1[j + 1], b1[j + 1]));
        h2v hv;
        hv.x = (_Float16)t0;
        hv.y = (_Float16)t1;
        hreg[j2] = hv;
    }
    __syncthreads();  // wd2l visible to all lanes

    // ---- layer 2: 4 chunks of 16 channels, v_dot2_f32_f16, f32 accumulators ----
    float sum2 = 0.f, sumsq2 = 0.f;
    float d2a[16], d2b[16], d2c[16], d2d[16];

#define CHUNK_BODY(J0, DST)                                                    \
    {                                                                          \
        _Pragma("unroll")                                                      \
        for (int j = 0; j < 16; j++) DST[j] = bd2[(J0) + j];                   \
        _Pragma("unroll")                                                      \
        for (int k2 = 0; k2 < 32; k2++) {                                      \
            h2v hk = hreg[k2];                                                 \
            _Pragma("unroll")                                                  \
            for (int j = 0; j < 16; j++)                                       \
                DST[j] = FDOT2(hk, wd2l[k2][(J0) + j], DST[j]);                \
        }                                                                      \
        _Pragma("unroll")                                                      \
        for (int j = 0; j < 16; j++) {                                         \
            float a = DST[j];                                                  \
            sum2 += a;                                                         \
            sumsq2 = fmaf(a, a, sumsq2);                                       \
        }                                                                      \
    }

    CHUNK_BODY(0, d2a)
    CHUNK_BODY(16, d2b)
    CHUNK_BODY(32, d2c)
    CHUNK_BODY(48, d2d)
#undef CHUNK_BODY

    float mu2 = sum2 * (1.0f / C);
    float var2 = fmaf(-mu2, mu2, sumsq2 * (1.0f / C));
    float rs2 = __builtin_amdgcn_rsqf(var2 + 1e-5f);

    // ---- LN2 + GELU in-register, pack final dv to bf16, write own LDS row ----
#define PACK_CHUNK(ARR, J0, W0)                                                \
    {                                                                          \
        _Pragma("unroll")                                                      \
        for (int j2 = 0; j2 < 8; j2++) {                                       \
            int j = (J0) + 2 * j2;                                             \
            float v0 = fast_gelu(fmaf((ARR[2 * j2] - mu2) * rs2, g2[j], b2[j])); \
            float v1 = fast_gelu(fmaf((ARR[2 * j2 + 1] - mu2) * rs2,           \
                                      g2[j + 1], b2[j + 1]));                  \
            d2buf[lane][(W0) + j2] = bfpack(v0, v1);                           \
        }                                                                      \
    }

    PACK_CHUNK(d2a, 0, 0)
    PACK_CHUNK(d2b, 16, 8)
    PACK_CHUNK(d2c, 32, 16)
    PACK_CHUNK(d2d, 48, 24)
#undef PACK_CHUNK
    __syncthreads();

    // ---- phase 2: lane = channel, iterate the window's sorted edges ----
    int cur_t = -1;
    bool owned = false;
    float den_a = 0.f, num_a = 0.f, w1v = 0.f;
#pragma unroll 4
    for (int i = 0; i < 64; i++) {
        int ti = __shfl(t_my, i);
        int si = __shfl(s_my, i);
        if (ti != cur_t) {
            if (cur_t >= 0) {
                size_t o = (size_t)cur_t * C + lane;
                if (owned) out[o] = num_a / den_a;
                else { unsafeAtomicAdd(&den[o], den_a); unsafeAtomicAdd(&out[o], num_a); }
            }
            cur_t = ti; den_a = 0.f; num_a = 0.f;
            w1v = w1[(size_t)ti * C + lane];
            int o0 = offsets[ti], o1 = offsets[ti + 1];
            owned = (o0 >= p0) && (o1 <= p0 + 64);
        }
        unsigned int hu = d2buf[i][lane >> 1];
        float dv = __uint_as_float((lane & 1) ? (hu & 0xffff0000u) : (hu << 16));
        float2 v23 = ((const float2*)w23)[(size_t)si * C + lane];
        float ee = __expf(w1v - v23.x + dv);
        den_a += ee;
        num_a = fmaf(ee, v23.y + dv, num_a);
    }
    {
        size_t o = (size_t)cur_t * C + lane;
        if (owned) out[o] = num_a / den_a;
        else { unsafeAtomicAdd(&den[o], den_a); unsafeAtomicAdd(&out[o], num_a); }
    }
}

// ---------- finalize: divide straddler targets (den > 0) ----------

__global__ __launch_bounds__(256) void finalize(float4* __restrict__ out,
                                                const float4* __restrict__ den) {
    int i = blockIdx.x * 256 + threadIdx.x;
    if (i >= MM * (C / 4)) return;
    float4 dn = den[i];
    if (dn.x == 0.f && dn.y == 0.f && dn.z == 0.f && dn.w == 0.f) return;
    float4 nm = out[i];
    float4 o;
    o.x = (dn.x != 0.f) ? nm.x / dn.x : nm.x;
    o.y = (dn.y != 0.f) ? nm.y / dn.y : nm.y;
    o.z = (dn.z != 0.f) ? nm.z / dn.z : nm.z;
    o.w = (dn.w != 0.f) ? nm.w / dn.w : nm.w;
    out[i] = o;
}

// ---------- launch ----------

extern "C" void kernel_launch(void* const* d_in, const int* in_sizes, int n_in,
                              void* d_out, int out_size, void* d_ws, size_t ws_size,
                              hipStream_t stream) {
    const int*   src  = (const int*)d_in[0];
    const int*   tgt  = (const int*)d_in[1];
    const float* feat = (const float*)d_in[2];
    const float* hood = (const float*)d_in[3];
    const float* Wd1  = (const float*)d_in[4];
    const float* bd1  = (const float*)d_in[5];
    const float* g1   = (const float*)d_in[6];
    const float* b1   = (const float*)d_in[7];
    const float* Wd2  = (const float*)d_in[8];
    const float* bd2  = (const float*)d_in[9];
    const float* g2   = (const float*)d_in[10];
    const float* b2   = (const float*)d_in[11];
    const float* W1   = (const float*)d_in[12];
    const float* W2   = (const float*)d_in[13];
    const float* W3   = (const float*)d_in[14];

    float* w1  = (float*)d_ws;
    float* w23 = w1 + (size_t)MM * C;
    float* den = w23 + (size_t)2 * MM * C;
    int* counts_cursor = (int*)(den + (size_t)MM * C);
    int* offsets = counts_cursor + 50176;
    int* se = offsets + (MM + 1);
    int* ss = se + EE;
    int* st = ss + EE;
    float* out = (float*)d_out;

    hipMemsetAsync(counts_cursor, 0, 50176 * sizeof(int), stream);
    hipMemsetAsync(den, 0, (size_t)MM * C * sizeof(float), stream);
    hipMemsetAsync(out, 0, (size_t)MM * C * sizeof(float), stream);

    node_proj<<<(MM * 16 + 255) / 256, 256, 0, stream>>>(feat, W1, W2, W3, w1, w23);
    count_kernel<<<(EE + 255) / 256, 256, 0, stream>>>(tgt, counts_cursor);
    scan_kernel<<<1, 1024, 0, stream>>>(counts_cursor, offsets);
    scatter_kernel<<<(EE + 255) / 256, 256, 0, stream>>>(src, tgt, counts_cursor, se, ss, st);
    main_kernel<<<NWIN, 64, 0, stream>>>(se, ss, st, offsets, hood,
                                         Wd1, bd1, g1, b1, Wd2, bd2, g2, b2,
                                         w1, w23, den, out);
    finalize<<<(MM * 16 + 255) / 256, 256, 0, stream>>>((float4*)out, (const float4*)den);
}